// Round 7
// baseline (498.539 us; speedup 1.0000x reference)
//
#include <hip/hip_runtime.h>
#include <cstdint>
#include <cstddef>

// ---------------------------------------------------------------------------
// BatchTreeEncoder on MFMA: A=4, D=7, B=64, E=128, H=128, N_NODES=5461
// Leaves (h0=0): H_leaf[v][128] precomputed once (bf16, bitwise-identical);
// level-5 attention gathers children from H_leaf and emits the leaf max with
// lane-contiguous atomics. Levels 5..0: attn_mfma + persistent gru_mfma.
// THIS ROUND: gru_mfma<true> was 1 block/CU (unified VGPR+AGPR = 192/wave;
// 96 regs were held B-fragments). B is now loop-loaded from L2 with 1-deep
// prefetch + __launch_bounds__(512,4) -> <=128 regs -> 2 blocks/CU.
// ---------------------------------------------------------------------------

typedef short  bf16x8 __attribute__((ext_vector_type(8)));
typedef float  f32x4  __attribute__((ext_vector_type(4)));

// workspace layout (bytes), total ~65 MB
#define WS_ACC    0u                         // 32*8192*4 = 1 MB
#define WS_WIH    1048576u                   // 384*128*2 = 96 KB
#define WS_WHH    (WS_WIH + 98304u)
#define WS_SWT    (WS_WHH + 98304u)          // 128*128*2 = 32 KB
#define WS_EMBB   (WS_SWT + 32768u)          // 50000*128*2 = 12.8 MB
#define WS_HLEAF  (WS_EMBB + 12800000u)      // 50000*128*2 = 12.8 MB
#define WS_HA     (WS_HLEAF + 12800000u)     // even levels out, max d=4: 4 MB
#define WS_HB     (WS_HA + 4194304u)         // odd levels out, max d=5: 16 MB
#define WS_H0     (WS_HB + 16777216u)        // attention out, max 16 MB

__device__ __forceinline__ float sigm(float x)   { return 1.0f / (1.0f + __expf(-x)); }
__device__ __forceinline__ float tanhf_(float x) { return 1.0f - 2.0f / (1.0f + __expf(2.0f * x)); }

__device__ __forceinline__ unsigned short f2b(float f) {
  unsigned u = __float_as_uint(f);
  u += 0x7fffu + ((u >> 16) & 1u);     // RNE (no NaN here)
  return (unsigned short)(u >> 16);
}
__device__ __forceinline__ float b2f(unsigned short s) {
  return __uint_as_float(((unsigned)s) << 16);
}

__device__ __forceinline__ unsigned fenc(float f) {
  unsigned u = __float_as_uint(f);
  return (u & 0x80000000u) ? ~u : (u | 0x80000000u);
}
__device__ __forceinline__ float fdec(unsigned e) {
  unsigned u = (e & 0x80000000u) ? (e & 0x7fffffffu) : ~e;
  return __uint_as_float(u);
}

__device__ __forceinline__ f32x4 mfma16(bf16x8 a, bf16x8 b, f32x4 c) {
  return __builtin_amdgcn_mfma_f32_16x16x32_bf16(a, b, c, 0, 0, 0);
}

__global__ __launch_bounds__(256) void decode_out(const unsigned* __restrict__ acc,
                                                  float* __restrict__ out) {
  int i = blockIdx.x * 256 + threadIdx.x;              // grid 32
  unsigned m = 0u;
  for (int s = 0; s < 32; ++s) m = max(m, acc[s * 8192 + i]);
  out[i] = fdec(m);
}

// one-shot prep: emb->bf16, weights->bf16, sent_w transpose, acc init
__global__ __launch_bounds__(256) void prep_all(const float* __restrict__ emb,
                                                const float* __restrict__ wih,
                                                const float* __restrict__ whh,
                                                const float* __restrict__ sw,
                                                unsigned short* __restrict__ embb,
                                                unsigned short* __restrict__ wihb,
                                                unsigned short* __restrict__ whhb,
                                                unsigned short* __restrict__ swtb,
                                                unsigned* __restrict__ acc) {
  size_t idx = (size_t)blockIdx.x * 256 + threadIdx.x;   // grid 7722
  if (idx < 1600000u) {                                  // 6.4M floats as float4
    float4 v = *(const float4*)(emb + idx * 4);
    ushort4 o; o.x = f2b(v.x); o.y = f2b(v.y); o.z = f2b(v.z); o.w = f2b(v.w);
    *(ushort4*)(embb + idx * 4) = o;
  } else if (idx < 1714688u) {                           // 114688 weight elems
    int i = (int)(idx - 1600000u);
    if (i < 49152)       wihb[i] = f2b(wih[i]);
    else if (i < 98304)  whhb[i - 49152] = f2b(whh[i - 49152]);
    else { int j = i - 98304; int k = j >> 7, h = j & 127; swtb[j] = f2b(sw[h * 128 + k]); }
  } else {                                               // 262144 acc words
    acc[idx - 1714688u] = 0u;
  }
}

// ---------------------------------------------------------------------------
// prep_hleaf: H_leaf[v][:] = leaf GRU output for token v (bitwise-identical
// to the old leaf path). grid 782 x 512. LDS-routed full-line stores.
// ---------------------------------------------------------------------------
__global__ __launch_bounds__(512, 2) void prep_hleaf(
    const unsigned short* __restrict__ embb,
    const unsigned short* __restrict__ wih,
    const float*          __restrict__ b_ih,
    const float*          __restrict__ b_hh,
    unsigned short*       __restrict__ H)
{
  __shared__ unsigned short lds[64 * 128];
  __shared__ unsigned short hvb[64 * 128];
  const int t = threadIdx.x;
  const int base = blockIdx.x * 64;

  // stage 64 sequential embb rows (XOR-swizzled 16B chunks)
#pragma unroll
  for (int i = 0; i < 2; ++i) {
    int g = t + 512 * i;
    int m = g >> 4, c = g & 15;
    int v = base + m; if (v > 49999) v = 49999;
    uint4 vv = *(const uint4*)(embb + (size_t)v * 128 + c * 8);
    *(uint4*)(lds + m * 128 + ((c ^ (m & 15)) << 3)) = vv;
  }

  const int w = __builtin_amdgcn_readfirstlane(t >> 6);
  const int lane = t & 63, l = lane & 15, q = lane >> 4;
  const int j = w * 16 + l;

  bf16x8 Br[4], Bz[4], Bn[4];
#pragma unroll
  for (int ks = 0; ks < 4; ++ks) {
    const int ko = ks * 32 + q * 8;
    Br[ks] = *(const bf16x8*)(wih + (size_t)j * 128 + ko);
    Bz[ks] = *(const bf16x8*)(wih + (size_t)(128 + j) * 128 + ko);
    Bn[ks] = *(const bf16x8*)(wih + (size_t)(256 + j) * 128 + ko);
  }
  const float bR = b_ih[j] + b_hh[j];
  const float bZ = b_ih[128 + j] + b_hh[128 + j];
  const float bN = b_ih[256 + j];
  const float bH = b_hh[256 + j];

  f32x4 Cr[4] = {{0,0,0,0},{0,0,0,0},{0,0,0,0},{0,0,0,0}};
  f32x4 Cz[4] = {{0,0,0,0},{0,0,0,0},{0,0,0,0},{0,0,0,0}};
  f32x4 Cn[4] = {{0,0,0,0},{0,0,0,0},{0,0,0,0},{0,0,0,0}};
  __syncthreads();

#pragma unroll
  for (int ks = 0; ks < 4; ++ks) {
    bf16x8 A[4];
#pragma unroll
    for (int mt = 0; mt < 4; ++mt) {
      int m = mt * 16 + l, c = ks * 4 + q;
      A[mt] = *(const bf16x8*)(lds + m * 128 + (((c ^ l) & 15) << 3));
    }
#pragma unroll
    for (int mt = 0; mt < 4; ++mt) {
      Cr[mt] = mfma16(A[mt], Br[ks], Cr[mt]);
      Cz[mt] = mfma16(A[mt], Bz[ks], Cz[mt]);
      Cn[mt] = mfma16(A[mt], Bn[ks], Cn[mt]);
    }
  }

#pragma unroll
  for (int mt = 0; mt < 4; ++mt)
#pragma unroll
    for (int e = 0; e < 4; ++e) {
      int b = mt * 16 + q * 4 + e;              // C/D: col=lane&15, row=quad*4+reg
      float r  = sigm(Cr[mt][e] + bR);
      float z  = sigm(Cz[mt][e] + bZ);
      float nv = tanhf_(Cn[mt][e] + bN + r * bH);
      float hv = (1.0f - z) * nv;
      hvb[b * 128 + (j ^ (q << 4))] = f2b(hv);
    }
  __syncthreads();

  // full-line stores
#pragma unroll
  for (int i = 0; i < 2; ++i) {
    int g = t + 512 * i;
    int b = g >> 4, c8 = (g & 15) * 8;
    int qq = (b >> 2) & 3;
    if (base + b < 50000) {
      uint4 v = *(const uint4*)(hvb + b * 128 + (c8 ^ (qq << 4)));
      *(uint4*)(H + (size_t)(base + b) * 128 + c8) = v;
    }
  }
}

// ---------------------------------------------------------------------------
// GRU (levels 5..0): persistent. Wave w owns 16 output cols j=w*16+l.
// B-fragments are LOOP-LOADED from L2 (1-deep prefetch) instead of held:
// saves 96 regs/wave -> <=128 total (unified VGPR+AGPR) -> 2 blocks/CU.
// A (x||h0) in LDS (XOR-swizzled); hv via hvb buffer -> full-line stores.
// ---------------------------------------------------------------------------
template <bool HAS_H>
__global__ __launch_bounds__(512, 4) void gru_mfma(
    const int*            __restrict__ tok,
    const unsigned short* __restrict__ embb,
    const unsigned short* __restrict__ wih,
    const unsigned short* __restrict__ whh,
    const float*          __restrict__ b_ih,
    const float*          __restrict__ b_hh,
    const unsigned short* __restrict__ h0,
    unsigned short*       __restrict__ hout,
    unsigned*             __restrict__ acc,
    int nNodes, int npb)
{
  constexpr int RS  = HAS_H ? 256 : 128;   // ushorts per LDS row
  constexpr int NKS = HAS_H ? 8 : 4;
  __shared__ unsigned short lds[64 * RS];      // A tile (x || h0)
  __shared__ unsigned short hvb[64 * 128];     // hv staging for full-line store

  const int t = threadIdx.x;
  const int nodeBeg = blockIdx.x * npb;
  const int nodeEnd = min(nNodes, nodeBeg + npb);

  const int w = __builtin_amdgcn_readfirstlane(t >> 6);
  const int lane = t & 63, l = lane & 15, q = lane >> 4;
  const int j = w * 16 + l;

  // per-thread staging coords (2 chunks each for x and h0)
  const int sm0 = t >> 4,          sc0 = t & 15;          // g = t
  const int sm1 = (t + 512) >> 4,  sc1 = (t + 512) & 15;  // g = t + 512

  // per-thread B row bases (gate triplet {j, 128+j, 256+j}, lane-chunk q*8)
  const unsigned short* wI = wih + (size_t)j * 128 + q * 8;
  const unsigned short* wH = whh + (size_t)j * 128 + q * 8;

  const float bR = b_ih[j] + b_hh[j];
  const float bZ = b_ih[128 + j] + b_hh[128 + j];
  const float bN = b_ih[256 + j];
  const float bH = b_hh[256 + j];

  float mx[4][4];
#pragma unroll
  for (int mt = 0; mt < 4; ++mt)
#pragma unroll
    for (int e = 0; e < 4; ++e) mx[mt][e] = -1e30f;

  // prefetch first node into regs
  uint4 px0, px1, ph0, ph1;
  {
    const int* tp = tok + nodeBeg * 64;
    px0 = *(const uint4*)(embb + (size_t)tp[sm0] * 128 + sc0 * 8);
    px1 = *(const uint4*)(embb + (size_t)tp[sm1] * 128 + sc1 * 8);
    if constexpr (HAS_H) {
      const unsigned short* hp = h0 + (size_t)nodeBeg * 8192;
      ph0 = *(const uint4*)(hp + sm0 * 128 + sc0 * 8);
      ph1 = *(const uint4*)(hp + sm1 * 128 + sc1 * 8);
    }
  }

  for (int node = nodeBeg; node < nodeEnd; ++node) {
    // A-write from prefetch regs (x chunks 0..15, h0 chunks 16..31)
    *(uint4*)(lds + sm0 * RS + ((sc0 ^ (sm0 & 15)) << 3)) = px0;
    *(uint4*)(lds + sm1 * RS + ((sc1 ^ (sm1 & 15)) << 3)) = px1;
    if constexpr (HAS_H) {
      *(uint4*)(lds + sm0 * 256 + ((16 | ((sc0 ^ (sm0 & 15)) & 15)) << 3)) = ph0;
      *(uint4*)(lds + sm1 * 256 + ((16 | ((sc1 ^ (sm1 & 15)) & 15)) << 3)) = ph1;
    }
    __syncthreads();

    // issue next node's staging loads (latency hidden under MFMA + epilogue)
    if (node + 1 < nodeEnd) {
      const int* tp = tok + (node + 1) * 64;
      px0 = *(const uint4*)(embb + (size_t)tp[sm0] * 128 + sc0 * 8);
      px1 = *(const uint4*)(embb + (size_t)tp[sm1] * 128 + sc1 * 8);
      if constexpr (HAS_H) {
        const unsigned short* hp = h0 + (size_t)(node + 1) * 8192;
        ph0 = *(const uint4*)(hp + sm0 * 128 + sc0 * 8);
        ph1 = *(const uint4*)(hp + sm1 * 128 + sc1 * 8);
      }
    }

    f32x4 Cr[4] = {{0,0,0,0},{0,0,0,0},{0,0,0,0},{0,0,0,0}};
    f32x4 Cz[4] = {{0,0,0,0},{0,0,0,0},{0,0,0,0},{0,0,0,0}};
    f32x4 Cn[4] = {{0,0,0,0},{0,0,0,0},{0,0,0,0},{0,0,0,0}};
    f32x4 Ch[4] = {{0,0,0,0},{0,0,0,0},{0,0,0,0},{0,0,0,0}};

    // B triple for ks=0 (from W_ih)
    bf16x8 b0 = *(const bf16x8*)(wI);
    bf16x8 b1 = *(const bf16x8*)(wI + 128 * 128);
    bf16x8 b2 = *(const bf16x8*)(wI + 256 * 128);

#pragma unroll
    for (int ks = 0; ks < NKS; ++ks) {
      bf16x8 c0 = b0, c1 = b1, c2 = b2;
      if (ks + 1 < NKS) {                       // prefetch next triple
        const int kk = ks + 1;
        const unsigned short* base = (HAS_H && kk >= 4) ? wH : wI;
        const int ko = (kk & 3) * 32;
        b0 = *(const bf16x8*)(base + ko);
        b1 = *(const bf16x8*)(base + 128 * 128 + ko);
        b2 = *(const bf16x8*)(base + 256 * 128 + ko);
      }
#pragma unroll
      for (int mt = 0; mt < 4; ++mt) {
        int m = mt * 16 + l;
        int c = ks * 4 + q;
        bf16x8 Amt = *(const bf16x8*)(lds + m * RS + (((c & 16) | ((c ^ l) & 15)) << 3));
        Cr[mt] = mfma16(Amt, c0, Cr[mt]);
        Cz[mt] = mfma16(Amt, c1, Cz[mt]);
        if (!HAS_H || ks < 4) Cn[mt] = mfma16(Amt, c2, Cn[mt]);
        else                  Ch[mt] = mfma16(Amt, c2, Ch[mt]);
      }
    }

    // gates in-register; hv -> hvb (q-swizzled cols); running max in regs
#pragma unroll
    for (int mt = 0; mt < 4; ++mt) {
#pragma unroll
      for (int e = 0; e < 4; ++e) {
        const int b = mt * 16 + q * 4 + e;      // C/D: col=lane&15, row=quad*4+reg
        float r  = sigm(Cr[mt][e] + bR);
        float z  = sigm(Cz[mt][e] + bZ);
        float hn_ = bH + (HAS_H ? Ch[mt][e] : 0.0f);
        float nv = tanhf_(Cn[mt][e] + bN + r * hn_);
        float hp = 0.0f;
        if constexpr (HAS_H) {
          int c16 = j >> 3;
          hp = b2f(lds[b * 256 + ((16 | ((c16 ^ (b & 15)) & 15)) << 3) + (j & 7)]);
        }
        float hv = (1.0f - z) * nv + z * hp;
        hvb[b * 128 + (j ^ (q << 4))] = f2b(hv);
        mx[mt][e] = fmaxf(mx[mt][e], hv);
      }
    }
    __syncthreads();   // A reads + hvb writes done

    // coalesced full-line hout store (reads hvb only; next A-write is disjoint)
    unsigned short* ho = hout + (size_t)node * 8192;
    {
      int b0s = sm0, c80 = sc0 * 8, q0 = (b0s >> 2) & 3;
      int b1s = sm1, c81 = sc1 * 8, q1 = (b1s >> 2) & 3;
      uint4 v0 = *(const uint4*)(hvb + b0s * 128 + (c80 ^ (q0 << 4)));
      uint4 v1 = *(const uint4*)(hvb + b1s * 128 + (c81 ^ (q1 << 4)));
      *(uint4*)(ho + b0s * 128 + c80) = v0;
      *(uint4*)(ho + b1s * 128 + c81) = v1;
    }
  }

  // one atomic set per block, at true kernel end (no barrier after)
  unsigned* accs = acc + (blockIdx.x & 31) * 8192;
#pragma unroll
  for (int mt = 0; mt < 4; ++mt)
#pragma unroll
    for (int e = 0; e < 4; ++e) {
      const int b = mt * 16 + q * 4 + e;
      atomicMax(accs + b * 128 + j, fenc(mx[mt][e]));
    }
}

// ---------------------------------------------------------------------------
// Attention: grid n (parents), block 512 (8 waves: wm=row-half, wn=col-chunk32).
// LEAF variant: child rows gathered straight from H_leaf via tokens; leaf max
// from the staged LDS tile with LANE-CONTIGUOUS atomics (word = t+512e).
// ---------------------------------------------------------------------------
template <bool LEAF>
__global__ __launch_bounds__(512, 2) void attn_mfma(
    const unsigned short* __restrict__ hch,   // child h (non-leaf), rows p*256..
    const unsigned short* __restrict__ swt,   // 128x128 bf16 [k_u][h]
    const float*          __restrict__ sb,
    const float*          __restrict__ ctx,
    unsigned short*       __restrict__ h0out,
    const int*            __restrict__ tok6,  // LEAF only
    const unsigned short* __restrict__ hleaf, // LEAF only
    unsigned*             __restrict__ acc)   // LEAF only
{
  __shared__ unsigned short chs[256 * 128];   // 64 KB, swizzled
  __shared__ float spart[4][256];
  __shared__ float alf[256];

  const int p = blockIdx.x;
  const int t = threadIdx.x;

  if constexpr (LEAF) {
    const int* tokp = tok6 + p * 256;
#pragma unroll
    for (int i = 0; i < 8; ++i) {
      int g = t + 512 * i;                    // 0..4095 16B-chunks
      int m = g >> 4, c = g & 15;
      int tv = tokp[m];
      uint4 v = *(const uint4*)(hleaf + (size_t)tv * 128 + c * 8);
      *(uint4*)(chs + m * 128 + ((c ^ (m & 15)) << 3)) = v;
    }
  } else {
    const unsigned short* src = hch + (size_t)p * 256 * 128;
#pragma unroll
    for (int i = 0; i < 8; ++i) {
      int g = t + 512 * i;                    // 0..4095 16B-chunks
      int m = g >> 4, c = g & 15;
      uint4 v = *(const uint4*)(src + m * 128 + c * 8);
      *(uint4*)(chs + m * 128 + ((c ^ (m & 15)) << 3)) = v;
    }
  }

  const int w = __builtin_amdgcn_readfirstlane(t >> 6);
  const int wm = w >> 2, wn = w & 3;
  const int lane = t & 63, l = lane & 15, q = lane >> 4;

  bf16x8 Bs[2][4];
#pragma unroll
  for (int nt = 0; nt < 2; ++nt)
#pragma unroll
    for (int ks = 0; ks < 4; ++ks)
      Bs[nt][ks] = *(const bf16x8*)(swt + (size_t)(wn * 32 + nt * 16 + l) * 128 + ks * 32 + q * 8);

  f32x4 Cu[8][2] = {};
  __syncthreads();

#pragma unroll
  for (int ks = 0; ks < 4; ++ks) {
#pragma unroll
    for (int mt = 0; mt < 8; ++mt) {
      int m = wm * 128 + mt * 16 + l;
      int c = ks * 4 + q;
      bf16x8 A = *(const bf16x8*)(chs + m * 128 + (((c ^ (m & 15)) & 15) << 3));
      Cu[mt][0] = mfma16(A, Bs[0][ks], Cu[mt][0]);
      Cu[mt][1] = mfma16(A, Bs[1][ks], Cu[mt][1]);
    }
  }

  const float sb0 = sb[wn * 32 + l],  sb1 = sb[wn * 32 + 16 + l];
  const float cx0 = ctx[wn * 32 + l], cx1 = ctx[wn * 32 + 16 + l];
#pragma unroll
  for (int mt = 0; mt < 8; ++mt) {
    float pe[4];
#pragma unroll
    for (int e = 0; e < 4; ++e)
      pe[e] = tanhf_(Cu[mt][0][e] + sb0) * cx0 + tanhf_(Cu[mt][1][e] + sb1) * cx1;
#pragma unroll
    for (int mask = 1; mask < 16; mask <<= 1)
#pragma unroll
      for (int e = 0; e < 4; ++e)
        pe[e] += __shfl_xor(pe[e], mask, 16);
    if (l == 0) {
      int r = wm * 128 + mt * 16 + q * 4;
#pragma unroll
      for (int e = 0; e < 4; ++e) spart[wn][r + e] = pe[e];
    }
  }
  __syncthreads();

  if (t < 256) {
    float s = tanhf_(spart[0][t] + spart[1][t] + spart[2][t] + spart[3][t]);
    spart[0][t] = s;                          // reuse row 0 as s-values
  }
  __syncthreads();
  if (t < 64) {
    float s0 = spart[0][t], s1 = spart[0][64 + t], s2 = spart[0][128 + t], s3 = spart[0][192 + t];
    float m = fmaxf(fmaxf(s0, s1), fmaxf(s2, s3));
    float e0 = __expf(s0 - m), e1 = __expf(s1 - m), e2 = __expf(s2 - m), e3 = __expf(s3 - m);
    float inv = 1.0f / (e0 + e1 + e2 + e3);
    alf[t] = e0 * inv; alf[64 + t] = e1 * inv; alf[128 + t] = e2 * inv; alf[192 + t] = e3 * inv;
  }
  __syncthreads();

#pragma unroll
  for (int i = 0; i < 2; ++i) {
    int id = t + 512 * i;                     // 0..1023: (b, chunk)
    int b = id >> 4, c = id & 15;
    float o[8] = {0,0,0,0,0,0,0,0};
#pragma unroll
    for (int a = 0; a < 4; ++a) {
      int m = a * 64 + b;
      const unsigned short* rp = chs + m * 128 + ((c ^ (m & 15)) << 3);
      float al = alf[a * 64 + b];
#pragma unroll
      for (int k = 0; k < 8; ++k) o[k] += al * b2f(rp[k]);
    }
    ushort4 o0, o1;
    o0.x = f2b(o[0]); o0.y = f2b(o[1]); o0.z = f2b(o[2]); o0.w = f2b(o[3]);
    o1.x = f2b(o[4]); o1.y = f2b(o[5]); o1.z = f2b(o[6]); o1.w = f2b(o[7]);
    *(ushort4*)(h0out + (size_t)(p * 64 + b) * 128 + c * 8)     = o0;
    *(ushort4*)(h0out + (size_t)(p * 64 + b) * 128 + c * 8 + 4) = o1;
  }

  if constexpr (LEAF) {
    // leaf-level max from the staged tile, LANE-CONTIGUOUS acc mapping:
    // thread t owns acc words {t + 512*e}: j = t&127 (fixed), b = (t>>7)+4e.
    const int jj = t & 127;
    const int c  = jj >> 3;
    float mxv[16];
#pragma unroll
    for (int e = 0; e < 16; ++e) mxv[e] = -1e30f;
#pragma unroll
    for (int a = 0; a < 4; ++a) {
#pragma unroll
      for (int e = 0; e < 16; ++e) {
        int b = (t >> 7) + 4 * e;
        int m = a * 64 + b;
        float v = b2f(chs[m * 128 + (((c ^ (m & 15)) & 15) << 3) + (jj & 7)]);
        mxv[e] = fmaxf(mxv[e], v);
      }
    }
    unsigned* accs = acc + (p & 31) * 8192;
#pragma unroll
    for (int e = 0; e < 16; ++e)
      atomicMax(accs + t + 512 * e, fenc(mxv[e]));
  }
}

extern "C" void kernel_launch(void* const* d_in, const int* in_sizes, int n_in,
                              void* d_out, int out_size, void* d_ws, size_t ws_size,
                              hipStream_t stream) {
  const int*   tokens = (const int*)d_in[0];
  const float* emb    = (const float*)d_in[1];
  const float* sent_w = (const float*)d_in[2];
  const float* sent_b = (const float*)d_in[3];
  const float* ctx_w  = (const float*)d_in[4];
  const float* w_ih   = (const float*)d_in[5];
  const float* w_hh   = (const float*)d_in[6];
  const float* b_ih   = (const float*)d_in[7];
  const float* b_hh   = (const float*)d_in[8];

  char* ws = (char*)d_ws;
  unsigned*       acc  = (unsigned*)(ws + WS_ACC);
  unsigned short* wihb = (unsigned short*)(ws + WS_WIH);
  unsigned short* whhb = (unsigned short*)(ws + WS_WHH);
  unsigned short* swtb = (unsigned short*)(ws + WS_SWT);
  unsigned short* embb = (unsigned short*)(ws + WS_EMBB);
  unsigned short* hlf  = (unsigned short*)(ws + WS_HLEAF);
  unsigned short* hA   = (unsigned short*)(ws + WS_HA);
  unsigned short* hB   = (unsigned short*)(ws + WS_HB);
  unsigned short* h0b  = (unsigned short*)(ws + WS_H0);

  hipLaunchKernelGGL(prep_all, dim3(7722), dim3(256), 0, stream,
                     emb, w_ih, w_hh, sent_w, embb, wihb, whhb, swtb, acc);
  hipLaunchKernelGGL(prep_hleaf, dim3(782), dim3(512), 0, stream,
                     embb, wihb, b_ih, b_hh, hlf);

  static const int offs[7] = {0, 1, 5, 21, 85, 341, 1365};
  const int* tok6 = tokens + (size_t)1365 * 64;

  for (int d = 5; d >= 0; --d) {
    int n = 1 << (2 * d);
    int off = offs[d];
    int npb  = (n + 511) / 512;                  // nodes per block
    int grid = (n + npb - 1) / npb;              // <=512, balanced chunks
    unsigned short* hout  = (d & 1) ? hB : hA;
    unsigned short* child = (d & 1) ? hA : hB;   // level d+1 output (non-leaf)
    if (d == 5) {
      hipLaunchKernelGGL((attn_mfma<true>), dim3(n), dim3(512), 0, stream,
                         (const unsigned short*)nullptr, swtb, sent_b, ctx_w,
                         h0b, tok6, hlf, acc);
    } else {
      hipLaunchKernelGGL((attn_mfma<false>), dim3(n), dim3(512), 0, stream,
                         child, swtb, sent_b, ctx_w, h0b,
                         (const int*)nullptr, (const unsigned short*)nullptr,
                         (unsigned*)nullptr);
    }
    hipLaunchKernelGGL((gru_mfma<true>), dim3(grid), dim3(512), 0, stream,
                       tokens + (size_t)off * 64, embb, wihb, whhb, b_ih, b_hh,
                       h0b, hout, acc, n, npb);
  }
  hipLaunchKernelGGL(decode_out, dim3(32), dim3(256), 0, stream, acc, (float*)d_out);
}

// Round 8
// 350.502 us; speedup vs baseline: 1.4224x; 1.4224x over previous
//
#include <hip/hip_runtime.h>
#include <cstdint>
#include <cstddef>

// ---------------------------------------------------------------------------
// BatchTreeEncoder on MFMA: A=4, D=7, B=64, E=128, H=128, N_NODES=5461
// Leaves (h0=0): H_leaf[v][128] precomputed once (bf16, bitwise-identical).
// Levels 5..0: ONE fused attn+gru kernel per level (block p: attention over
// its 4 children -> h0 kept in REGISTERS -> gru for node p). The h0 global
// round-trip and half the launches are gone. LDS phase-aliased: child tile
// chs (64 KB) is reused as the gru A-tile (32 KB) + hv staging (16 KB) after
// the alpha-weighted sum and leaf-max move to registers. Atomics only at
// true kernel end (lane-contiguous for the leaf set). No forced occupancy
// bounds: round-7 showed (512,4) causes scratch spills (+150 MB sym traffic).
// ---------------------------------------------------------------------------

typedef short  bf16x8 __attribute__((ext_vector_type(8)));
typedef float  f32x4  __attribute__((ext_vector_type(4)));

// workspace layout (bytes), total ~50 MB
#define WS_ACC    0u                         // 32*8192*4 = 1 MB
#define WS_WIH    1048576u                   // 384*128*2 = 96 KB
#define WS_WHH    (WS_WIH + 98304u)
#define WS_SWT    (WS_WHH + 98304u)          // 128*128*2 = 32 KB
#define WS_EMBB   (WS_SWT + 32768u)          // 50000*128*2 = 12.8 MB
#define WS_HLEAF  (WS_EMBB + 12800000u)      // 50000*128*2 = 12.8 MB
#define WS_HA     (WS_HLEAF + 12800000u)     // even levels out, max d=4: 4 MB
#define WS_HB     (WS_HA + 4194304u)         // odd levels out, max d=5: 16 MB

__device__ __forceinline__ float sigm(float x)   { return 1.0f / (1.0f + __expf(-x)); }
__device__ __forceinline__ float tanhf_(float x) { return 1.0f - 2.0f / (1.0f + __expf(2.0f * x)); }

__device__ __forceinline__ unsigned short f2b(float f) {
  unsigned u = __float_as_uint(f);
  u += 0x7fffu + ((u >> 16) & 1u);     // RNE (no NaN here)
  return (unsigned short)(u >> 16);
}
__device__ __forceinline__ float b2f(unsigned short s) {
  return __uint_as_float(((unsigned)s) << 16);
}

__device__ __forceinline__ unsigned fenc(float f) {
  unsigned u = __float_as_uint(f);
  return (u & 0x80000000u) ? ~u : (u | 0x80000000u);
}
__device__ __forceinline__ float fdec(unsigned e) {
  unsigned u = (e & 0x80000000u) ? (e & 0x7fffffffu) : ~e;
  return __uint_as_float(u);
}

__device__ __forceinline__ f32x4 mfma16(bf16x8 a, bf16x8 b, f32x4 c) {
  return __builtin_amdgcn_mfma_f32_16x16x32_bf16(a, b, c, 0, 0, 0);
}

__global__ __launch_bounds__(256) void decode_out(const unsigned* __restrict__ acc,
                                                  float* __restrict__ out) {
  int i = blockIdx.x * 256 + threadIdx.x;              // grid 32
  unsigned m = 0u;
  for (int s = 0; s < 32; ++s) m = max(m, acc[s * 8192 + i]);
  out[i] = fdec(m);
}

// one-shot prep: emb->bf16, weights->bf16, sent_w transpose, acc init
__global__ __launch_bounds__(256) void prep_all(const float* __restrict__ emb,
                                                const float* __restrict__ wih,
                                                const float* __restrict__ whh,
                                                const float* __restrict__ sw,
                                                unsigned short* __restrict__ embb,
                                                unsigned short* __restrict__ wihb,
                                                unsigned short* __restrict__ whhb,
                                                unsigned short* __restrict__ swtb,
                                                unsigned* __restrict__ acc) {
  size_t idx = (size_t)blockIdx.x * 256 + threadIdx.x;   // grid 7722
  if (idx < 1600000u) {                                  // 6.4M floats as float4
    float4 v = *(const float4*)(emb + idx * 4);
    ushort4 o; o.x = f2b(v.x); o.y = f2b(v.y); o.z = f2b(v.z); o.w = f2b(v.w);
    *(ushort4*)(embb + idx * 4) = o;
  } else if (idx < 1714688u) {                           // 114688 weight elems
    int i = (int)(idx - 1600000u);
    if (i < 49152)       wihb[i] = f2b(wih[i]);
    else if (i < 98304)  whhb[i - 49152] = f2b(whh[i - 49152]);
    else { int j = i - 98304; int k = j >> 7, h = j & 127; swtb[j] = f2b(sw[h * 128 + k]); }
  } else {                                               // 262144 acc words
    acc[idx - 1714688u] = 0u;
  }
}

// ---------------------------------------------------------------------------
// prep_hleaf: H_leaf[v][:] = leaf GRU output for token v (bitwise-identical
// to the old leaf path). grid 782 x 512. LDS-routed full-line stores.
// ---------------------------------------------------------------------------
__global__ __launch_bounds__(512, 2) void prep_hleaf(
    const unsigned short* __restrict__ embb,
    const unsigned short* __restrict__ wih,
    const float*          __restrict__ b_ih,
    const float*          __restrict__ b_hh,
    unsigned short*       __restrict__ H)
{
  __shared__ unsigned short lds[64 * 128];
  __shared__ unsigned short hvb[64 * 128];
  const int t = threadIdx.x;
  const int base = blockIdx.x * 64;

  // stage 64 sequential embb rows (XOR-swizzled 16B chunks)
#pragma unroll
  for (int i = 0; i < 2; ++i) {
    int g = t + 512 * i;
    int m = g >> 4, c = g & 15;
    int v = base + m; if (v > 49999) v = 49999;
    uint4 vv = *(const uint4*)(embb + (size_t)v * 128 + c * 8);
    *(uint4*)(lds + m * 128 + ((c ^ (m & 15)) << 3)) = vv;
  }

  const int w = __builtin_amdgcn_readfirstlane(t >> 6);
  const int lane = t & 63, l = lane & 15, q = lane >> 4;
  const int j = w * 16 + l;

  bf16x8 Br[4], Bz[4], Bn[4];
#pragma unroll
  for (int ks = 0; ks < 4; ++ks) {
    const int ko = ks * 32 + q * 8;
    Br[ks] = *(const bf16x8*)(wih + (size_t)j * 128 + ko);
    Bz[ks] = *(const bf16x8*)(wih + (size_t)(128 + j) * 128 + ko);
    Bn[ks] = *(const bf16x8*)(wih + (size_t)(256 + j) * 128 + ko);
  }
  const float bR = b_ih[j] + b_hh[j];
  const float bZ = b_ih[128 + j] + b_hh[128 + j];
  const float bN = b_ih[256 + j];
  const float bH = b_hh[256 + j];

  f32x4 Cr[4] = {{0,0,0,0},{0,0,0,0},{0,0,0,0},{0,0,0,0}};
  f32x4 Cz[4] = {{0,0,0,0},{0,0,0,0},{0,0,0,0},{0,0,0,0}};
  f32x4 Cn[4] = {{0,0,0,0},{0,0,0,0},{0,0,0,0},{0,0,0,0}};
  __syncthreads();

#pragma unroll
  for (int ks = 0; ks < 4; ++ks) {
    bf16x8 A[4];
#pragma unroll
    for (int mt = 0; mt < 4; ++mt) {
      int m = mt * 16 + l, c = ks * 4 + q;
      A[mt] = *(const bf16x8*)(lds + m * 128 + (((c ^ l) & 15) << 3));
    }
#pragma unroll
    for (int mt = 0; mt < 4; ++mt) {
      Cr[mt] = mfma16(A[mt], Br[ks], Cr[mt]);
      Cz[mt] = mfma16(A[mt], Bz[ks], Cz[mt]);
      Cn[mt] = mfma16(A[mt], Bn[ks], Cn[mt]);
    }
  }

#pragma unroll
  for (int mt = 0; mt < 4; ++mt)
#pragma unroll
    for (int e = 0; e < 4; ++e) {
      int b = mt * 16 + q * 4 + e;              // C/D: col=lane&15, row=quad*4+reg
      float r  = sigm(Cr[mt][e] + bR);
      float z  = sigm(Cz[mt][e] + bZ);
      float nv = tanhf_(Cn[mt][e] + bN + r * bH);
      float hv = (1.0f - z) * nv;
      hvb[b * 128 + (j ^ (q << 4))] = f2b(hv);
    }
  __syncthreads();

  // full-line stores
#pragma unroll
  for (int i = 0; i < 2; ++i) {
    int g = t + 512 * i;
    int b = g >> 4, c8 = (g & 15) * 8;
    int qq = (b >> 2) & 3;
    if (base + b < 50000) {
      uint4 v = *(const uint4*)(hvb + b * 128 + (c8 ^ (qq << 4)));
      *(uint4*)(H + (size_t)(base + b) * 128 + c8) = v;
    }
  }
}

// ---------------------------------------------------------------------------
// FUSED attn+gru: grid n (parents), block 512 (8 waves).
// Phase A (attn): stage 4 children (LEAF: gathered from H_leaf via tokens)
//   into chs; u = ch·sent_w via MFMA; s = tanh(sum tanh(u+sb)*ctx); softmax;
//   h0 = sum_a alpha_a*ch_a  -> REGISTERS.  LEAF: child max -> registers.
// Phase B (gru): A-tile (x||h0) built in chs[0..32K) (x prefetched at block
//   start, h0 from regs); MFMA over K=256; gates; hv -> chs[32K..48K) ->
//   full-line hout store. Atomics once at true kernel end.
// ---------------------------------------------------------------------------
template <bool LEAF>
__global__ __launch_bounds__(512, 2) void attn_gru(
    const unsigned short* __restrict__ hch,   // child h (non-leaf), rows p*256..
    const int*            __restrict__ tokc,  // LEAF: children tokens
    const unsigned short* __restrict__ hleaf, // LEAF: per-vocab leaf h
    const unsigned short* __restrict__ swt,   // 128x128 bf16 [k_u][h]
    const float*          __restrict__ sb,
    const float*          __restrict__ ctx,
    const int*            __restrict__ tok,   // THIS level's tokens
    const unsigned short* __restrict__ embb,
    const unsigned short* __restrict__ wih,
    const unsigned short* __restrict__ whh,
    const float*          __restrict__ b_ih,
    const float*          __restrict__ b_hh,
    unsigned short*       __restrict__ hout,
    unsigned*             __restrict__ acc)
{
  __shared__ unsigned short chs[256 * 128];   // 64 KB, phase-aliased
  __shared__ float spart[4][256];
  __shared__ float alf[256];
  unsigned short* const atile = chs;          // phase B: 64x256 A tile (32 KB)
  unsigned short* const hvb   = chs + 16384;  // phase B: hv staging (16 KB)

  const int p = blockIdx.x;
  const int t = threadIdx.x;

  // x gather for THIS node — issued at block start, consumed in phase B
  const int sm0 = t >> 4,         sc0 = t & 15;
  const int sm1 = (t + 512) >> 4, sc1 = (t + 512) & 15;
  const int* tp = tok + p * 64;
  uint4 px0 = *(const uint4*)(embb + (size_t)tp[sm0] * 128 + sc0 * 8);
  uint4 px1 = *(const uint4*)(embb + (size_t)tp[sm1] * 128 + sc1 * 8);

  // stage 256 child rows into chs (XOR-swizzled 16B chunks)
  if constexpr (LEAF) {
    const int* tokp = tokc + p * 256;
#pragma unroll
    for (int i = 0; i < 8; ++i) {
      int g = t + 512 * i, m = g >> 4, c = g & 15;
      uint4 v = *(const uint4*)(hleaf + (size_t)tokp[m] * 128 + c * 8);
      *(uint4*)(chs + m * 128 + ((c ^ (m & 15)) << 3)) = v;
    }
  } else {
    const unsigned short* src = hch + (size_t)p * 256 * 128;
#pragma unroll
    for (int i = 0; i < 8; ++i) {
      int g = t + 512 * i, m = g >> 4, c = g & 15;
      uint4 v = *(const uint4*)(src + m * 128 + c * 8);
      *(uint4*)(chs + m * 128 + ((c ^ (m & 15)) << 3)) = v;
    }
  }

  const int w = __builtin_amdgcn_readfirstlane(t >> 6);
  const int wm = w >> 2, wn = w & 3;
  const int lane = t & 63, l = lane & 15, q = lane >> 4;
  const int j = w * 16 + l;

  bf16x8 Bs[2][4];
#pragma unroll
  for (int nt = 0; nt < 2; ++nt)
#pragma unroll
    for (int ks = 0; ks < 4; ++ks)
      Bs[nt][ks] = *(const bf16x8*)(swt + (size_t)(wn * 32 + nt * 16 + l) * 128 + ks * 32 + q * 8);

  f32x4 Cu[8][2] = {};
  __syncthreads();                                          // (1) chs staged

#pragma unroll
  for (int ks = 0; ks < 4; ++ks) {
#pragma unroll
    for (int mt = 0; mt < 8; ++mt) {
      int m = wm * 128 + mt * 16 + l;
      int c = ks * 4 + q;
      bf16x8 A = *(const bf16x8*)(chs + m * 128 + (((c ^ (m & 15)) & 15) << 3));
      Cu[mt][0] = mfma16(A, Bs[0][ks], Cu[mt][0]);
      Cu[mt][1] = mfma16(A, Bs[1][ks], Cu[mt][1]);
    }
  }

  const float sb0 = sb[wn * 32 + l],  sb1 = sb[wn * 32 + 16 + l];
  const float cx0 = ctx[wn * 32 + l], cx1 = ctx[wn * 32 + 16 + l];
#pragma unroll
  for (int mt = 0; mt < 8; ++mt) {
    float pe[4];
#pragma unroll
    for (int e = 0; e < 4; ++e)
      pe[e] = tanhf_(Cu[mt][0][e] + sb0) * cx0 + tanhf_(Cu[mt][1][e] + sb1) * cx1;
#pragma unroll
    for (int mask = 1; mask < 16; mask <<= 1)
#pragma unroll
      for (int e = 0; e < 4; ++e)
        pe[e] += __shfl_xor(pe[e], mask, 16);
    if (l == 0) {
      int r = wm * 128 + mt * 16 + q * 4;
#pragma unroll
      for (int e = 0; e < 4; ++e) spart[wn][r + e] = pe[e];
    }
  }
  __syncthreads();                                          // (2)

  if (t < 256) {
    float s = tanhf_(spart[0][t] + spart[1][t] + spart[2][t] + spart[3][t]);
    spart[0][t] = s;
  }
  __syncthreads();                                          // (3)
  if (t < 64) {
    float s0 = spart[0][t], s1 = spart[0][64 + t], s2 = spart[0][128 + t], s3 = spart[0][192 + t];
    float m = fmaxf(fmaxf(s0, s1), fmaxf(s2, s3));
    float e0 = __expf(s0 - m), e1 = __expf(s1 - m), e2 = __expf(s2 - m), e3 = __expf(s3 - m);
    float inv = 1.0f / (e0 + e1 + e2 + e3);
    alf[t] = e0 * inv; alf[64 + t] = e1 * inv; alf[128 + t] = e2 * inv; alf[192 + t] = e3 * inv;
  }
  __syncthreads();                                          // (4)

  // alpha-weighted sum -> REGISTERS (this node's h0 rows)
  float o[2][8];
#pragma unroll
  for (int i = 0; i < 2; ++i) {
    int id = t + 512 * i, b = id >> 4, c = id & 15;
#pragma unroll
    for (int k = 0; k < 8; ++k) o[i][k] = 0.0f;
#pragma unroll
    for (int a = 0; a < 4; ++a) {
      int m = a * 64 + b;
      const unsigned short* rp = chs + m * 128 + ((c ^ (m & 15)) << 3);
      float al = alf[m];
#pragma unroll
      for (int k = 0; k < 8; ++k) o[i][k] += al * b2f(rp[k]);
    }
  }

  // LEAF: children-level max from chs, lane-contiguous mapping (word t+512e)
  float mxv[16];
  if constexpr (LEAF) {
    const int jj = t & 127, cc = jj >> 3;
#pragma unroll
    for (int e = 0; e < 16; ++e) mxv[e] = -1e30f;
#pragma unroll
    for (int a = 0; a < 4; ++a)
#pragma unroll
      for (int e = 0; e < 16; ++e) {
        int b = (t >> 7) + 4 * e, m = a * 64 + b;
        float v = b2f(chs[m * 128 + (((cc ^ (m & 15)) & 15) << 3) + (jj & 7)]);
        mxv[e] = fmaxf(mxv[e], v);
      }
  }
  __syncthreads();                                          // (5) chs reads done

  // build gru A tile (x chunks 0..15 || h0 chunks 16..31) in chs[0..32K)
  *(uint4*)(atile + sm0 * 256 + ((sc0 ^ (sm0 & 15)) << 3)) = px0;
  *(uint4*)(atile + sm1 * 256 + ((sc1 ^ (sm1 & 15)) << 3)) = px1;
#pragma unroll
  for (int i = 0; i < 2; ++i) {
    int id = t + 512 * i, b = id >> 4, c = id & 15;
    ushort4 h0a, h0b4;
    h0a.x = f2b(o[i][0]); h0a.y = f2b(o[i][1]); h0a.z = f2b(o[i][2]); h0a.w = f2b(o[i][3]);
    h0b4.x = f2b(o[i][4]); h0b4.y = f2b(o[i][5]); h0b4.z = f2b(o[i][6]); h0b4.w = f2b(o[i][7]);
    unsigned short* dst = atile + b * 256 + ((16 | ((c ^ (b & 15)) & 15)) << 3);
    *(ushort4*)dst = h0a;
    *(ushort4*)(dst + 4) = h0b4;
  }

  // gru B fragments (held in regs; loads overlap the barrier)
  bf16x8 Br[8], Bz[8], Bn[4], Bh[4];
#pragma unroll
  for (int ks = 0; ks < 4; ++ks) {
    const int ko = ks * 32 + q * 8;
    Br[ks]     = *(const bf16x8*)(wih + (size_t)j * 128 + ko);
    Bz[ks]     = *(const bf16x8*)(wih + (size_t)(128 + j) * 128 + ko);
    Bn[ks]     = *(const bf16x8*)(wih + (size_t)(256 + j) * 128 + ko);
    Br[4 + ks] = *(const bf16x8*)(whh + (size_t)j * 128 + ko);
    Bz[4 + ks] = *(const bf16x8*)(whh + (size_t)(128 + j) * 128 + ko);
    Bh[ks]     = *(const bf16x8*)(whh + (size_t)(256 + j) * 128 + ko);
  }
  const float bR = b_ih[j] + b_hh[j];
  const float bZ = b_ih[128 + j] + b_hh[128 + j];
  const float bN = b_ih[256 + j];
  const float bH = b_hh[256 + j];
  __syncthreads();                                          // (6) A tile ready

  f32x4 Cr[4] = {{0,0,0,0},{0,0,0,0},{0,0,0,0},{0,0,0,0}};
  f32x4 Cz[4] = {{0,0,0,0},{0,0,0,0},{0,0,0,0},{0,0,0,0}};
  f32x4 Cn[4] = {{0,0,0,0},{0,0,0,0},{0,0,0,0},{0,0,0,0}};
  f32x4 Ch[4] = {{0,0,0,0},{0,0,0,0},{0,0,0,0},{0,0,0,0}};

#pragma unroll
  for (int ks = 0; ks < 8; ++ks) {
#pragma unroll
    for (int mt = 0; mt < 4; ++mt) {
      int m = mt * 16 + l;
      int c = ks * 4 + q;
      bf16x8 Amt = *(const bf16x8*)(atile + m * 256 + (((c & 16) | ((c ^ l) & 15)) << 3));
      Cr[mt] = mfma16(Amt, Br[ks], Cr[mt]);
      Cz[mt] = mfma16(Amt, Bz[ks], Cz[mt]);
      if (ks < 4) Cn[mt] = mfma16(Amt, Bn[ks], Cn[mt]);
      else        Ch[mt] = mfma16(Amt, Bh[ks - 4], Ch[mt]);
    }
  }

  // gates; hv -> hvb (q-swizzled); per-thread max in regs
  float mx[4][4];
#pragma unroll
  for (int mt = 0; mt < 4; ++mt) {
#pragma unroll
    for (int e = 0; e < 4; ++e) {
      const int b = mt * 16 + q * 4 + e;        // C/D: col=lane&15, row=quad*4+reg
      float r  = sigm(Cr[mt][e] + bR);
      float z  = sigm(Cz[mt][e] + bZ);
      float nv = tanhf_(Cn[mt][e] + bN + r * (Ch[mt][e] + bH));
      int c16 = j >> 3;
      float hp = b2f(atile[b * 256 + ((16 | ((c16 ^ (b & 15)) & 15)) << 3) + (j & 7)]);
      float hv = (1.0f - z) * nv + z * hp;
      hvb[b * 128 + (j ^ (q << 4))] = f2b(hv);
      mx[mt][e] = hv;
    }
  }
  __syncthreads();                                          // (7) hvb ready

  // coalesced full-line hout store
  unsigned short* ho = hout + (size_t)p * 8192;
  {
    int c80 = sc0 * 8, q0 = (sm0 >> 2) & 3;
    int c81 = sc1 * 8, q1 = (sm1 >> 2) & 3;
    uint4 v0 = *(const uint4*)(hvb + sm0 * 128 + (c80 ^ (q0 << 4)));
    uint4 v1 = *(const uint4*)(hvb + sm1 * 128 + (c81 ^ (q1 << 4)));
    *(uint4*)(ho + sm0 * 128 + c80) = v0;
    *(uint4*)(ho + sm1 * 128 + c81) = v1;
  }

  // atomics at TRUE kernel end (no barrier after)
  unsigned* accs = acc + (p & 31) * 8192;
#pragma unroll
  for (int mt = 0; mt < 4; ++mt)
#pragma unroll
    for (int e = 0; e < 4; ++e) {
      const int b = mt * 16 + q * 4 + e;
      atomicMax(accs + b * 128 + j, fenc(mx[mt][e]));
    }
  if constexpr (LEAF) {
#pragma unroll
    for (int e = 0; e < 16; ++e)
      atomicMax(accs + t + 512 * e, fenc(mxv[e]));
  }
}

extern "C" void kernel_launch(void* const* d_in, const int* in_sizes, int n_in,
                              void* d_out, int out_size, void* d_ws, size_t ws_size,
                              hipStream_t stream) {
  const int*   tokens = (const int*)d_in[0];
  const float* emb    = (const float*)d_in[1];
  const float* sent_w = (const float*)d_in[2];
  const float* sent_b = (const float*)d_in[3];
  const float* ctx_w  = (const float*)d_in[4];
  const float* w_ih   = (const float*)d_in[5];
  const float* w_hh   = (const float*)d_in[6];
  const float* b_ih   = (const float*)d_in[7];
  const float* b_hh   = (const float*)d_in[8];

  char* ws = (char*)d_ws;
  unsigned*       acc  = (unsigned*)(ws + WS_ACC);
  unsigned short* wihb = (unsigned short*)(ws + WS_WIH);
  unsigned short* whhb = (unsigned short*)(ws + WS_WHH);
  unsigned short* swtb = (unsigned short*)(ws + WS_SWT);
  unsigned short* embb = (unsigned short*)(ws + WS_EMBB);
  unsigned short* hlf  = (unsigned short*)(ws + WS_HLEAF);
  unsigned short* hA   = (unsigned short*)(ws + WS_HA);
  unsigned short* hB   = (unsigned short*)(ws + WS_HB);

  hipLaunchKernelGGL(prep_all, dim3(7722), dim3(256), 0, stream,
                     emb, w_ih, w_hh, sent_w, embb, wihb, whhb, swtb, acc);
  hipLaunchKernelGGL(prep_hleaf, dim3(782), dim3(512), 0, stream,
                     embb, wihb, b_ih, b_hh, hlf);

  static const int offs[7] = {0, 1, 5, 21, 85, 341, 1365};
  const int* tok6 = tokens + (size_t)1365 * 64;

  for (int d = 5; d >= 0; --d) {
    int n = 1 << (2 * d);
    unsigned short* hout  = (d & 1) ? hB : hA;
    unsigned short* child = (d & 1) ? hA : hB;   // level d+1 output (non-leaf)
    if (d == 5) {
      hipLaunchKernelGGL((attn_gru<true>), dim3(n), dim3(512), 0, stream,
                         (const unsigned short*)nullptr, tok6, hlf,
                         swtb, sent_b, ctx_w,
                         tokens + (size_t)offs[5] * 64, embb, wihb, whhb,
                         b_ih, b_hh, hout, acc);
    } else {
      hipLaunchKernelGGL((attn_gru<false>), dim3(n), dim3(512), 0, stream,
                         child, (const int*)nullptr, (const unsigned short*)nullptr,
                         swtb, sent_b, ctx_w,
                         tokens + (size_t)offs[d] * 64, embb, wihb, whhb,
                         b_ih, b_hh, hout, acc);
    }
  }
  hipLaunchKernelGGL(decode_out, dim3(32), dim3(256), 0, stream, acc, (float*)d_out);
}

// Round 9
// 309.379 us; speedup vs baseline: 1.6114x; 1.1329x over previous
//
#include <hip/hip_runtime.h>
#include <cstdint>
#include <cstddef>

// ---------------------------------------------------------------------------
// BatchTreeEncoder on MFMA: A=4, D=7, B=64, E=128, H=128, N_NODES=5461
// Leaves: H_leaf[v][128] precomputed once (bf16, bitwise-identical).
// Levels 5..0: fused attn+gru, HALF-NODE blocks (grid 2n, 32 batch rows per
// block -> regs ~100 unified, 2 blocks/CU at (512,4); round-8 full-node
// version was 180 regs = 1 block/CU = latency-bound at 21% occupancy).
// Attention/softmax/h0/gru are independent per batch row, so the split is
// exact. gru B-fragments loop-loaded from L2 (1-deep prefetch). Atomics at
// true kernel end only (lane-contiguous for the leaf set).
// ---------------------------------------------------------------------------

typedef short  bf16x8 __attribute__((ext_vector_type(8)));
typedef float  f32x4  __attribute__((ext_vector_type(4)));

// workspace layout (bytes), total ~50 MB
#define WS_ACC    0u                         // 32*8192*4 = 1 MB
#define WS_WIH    1048576u                   // 384*128*2 = 96 KB
#define WS_WHH    (WS_WIH + 98304u)
#define WS_SWT    (WS_WHH + 98304u)          // 128*128*2 = 32 KB
#define WS_EMBB   (WS_SWT + 32768u)          // 50000*128*2 = 12.8 MB
#define WS_HLEAF  (WS_EMBB + 12800000u)      // 50000*128*2 = 12.8 MB
#define WS_HA     (WS_HLEAF + 12800000u)     // even levels out, max d=4: 4 MB
#define WS_HB     (WS_HA + 4194304u)         // odd levels out, max d=5: 16 MB

__device__ __forceinline__ float sigm(float x)   { return 1.0f / (1.0f + __expf(-x)); }
__device__ __forceinline__ float tanhf_(float x) { return 1.0f - 2.0f / (1.0f + __expf(2.0f * x)); }

__device__ __forceinline__ unsigned short f2b(float f) {
  unsigned u = __float_as_uint(f);
  u += 0x7fffu + ((u >> 16) & 1u);     // RNE (no NaN here)
  return (unsigned short)(u >> 16);
}
__device__ __forceinline__ float b2f(unsigned short s) {
  return __uint_as_float(((unsigned)s) << 16);
}

__device__ __forceinline__ unsigned fenc(float f) {
  unsigned u = __float_as_uint(f);
  return (u & 0x80000000u) ? ~u : (u | 0x80000000u);
}
__device__ __forceinline__ float fdec(unsigned e) {
  unsigned u = (e & 0x80000000u) ? (e & 0x7fffffffu) : ~e;
  return __uint_as_float(u);
}

__device__ __forceinline__ f32x4 mfma16(bf16x8 a, bf16x8 b, f32x4 c) {
  return __builtin_amdgcn_mfma_f32_16x16x32_bf16(a, b, c, 0, 0, 0);
}

__global__ __launch_bounds__(256) void decode_out(const unsigned* __restrict__ acc,
                                                  float* __restrict__ out) {
  int i = blockIdx.x * 256 + threadIdx.x;              // grid 32
  unsigned m = 0u;
  for (int s = 0; s < 32; ++s) m = max(m, acc[s * 8192 + i]);
  out[i] = fdec(m);
}

// one-shot prep: emb->bf16, weights->bf16, sent_w transpose, acc init
__global__ __launch_bounds__(256) void prep_all(const float* __restrict__ emb,
                                                const float* __restrict__ wih,
                                                const float* __restrict__ whh,
                                                const float* __restrict__ sw,
                                                unsigned short* __restrict__ embb,
                                                unsigned short* __restrict__ wihb,
                                                unsigned short* __restrict__ whhb,
                                                unsigned short* __restrict__ swtb,
                                                unsigned* __restrict__ acc) {
  size_t idx = (size_t)blockIdx.x * 256 + threadIdx.x;   // grid 7722
  if (idx < 1600000u) {                                  // 6.4M floats as float4
    float4 v = *(const float4*)(emb + idx * 4);
    ushort4 o; o.x = f2b(v.x); o.y = f2b(v.y); o.z = f2b(v.z); o.w = f2b(v.w);
    *(ushort4*)(embb + idx * 4) = o;
  } else if (idx < 1714688u) {                           // 114688 weight elems
    int i = (int)(idx - 1600000u);
    if (i < 49152)       wihb[i] = f2b(wih[i]);
    else if (i < 98304)  whhb[i - 49152] = f2b(whh[i - 49152]);
    else { int j = i - 98304; int k = j >> 7, h = j & 127; swtb[j] = f2b(sw[h * 128 + k]); }
  } else {                                               // 262144 acc words
    acc[idx - 1714688u] = 0u;
  }
}

// ---------------------------------------------------------------------------
// prep_hleaf: H_leaf[v][:] = leaf GRU output for token v (bitwise-identical
// to the old leaf path). grid 782 x 512. LDS-routed full-line stores.
// ---------------------------------------------------------------------------
__global__ __launch_bounds__(512, 2) void prep_hleaf(
    const unsigned short* __restrict__ embb,
    const unsigned short* __restrict__ wih,
    const float*          __restrict__ b_ih,
    const float*          __restrict__ b_hh,
    unsigned short*       __restrict__ H)
{
  __shared__ unsigned short lds[64 * 128];
  __shared__ unsigned short hvb[64 * 128];
  const int t = threadIdx.x;
  const int base = blockIdx.x * 64;

#pragma unroll
  for (int i = 0; i < 2; ++i) {
    int g = t + 512 * i;
    int m = g >> 4, c = g & 15;
    int v = base + m; if (v > 49999) v = 49999;
    uint4 vv = *(const uint4*)(embb + (size_t)v * 128 + c * 8);
    *(uint4*)(lds + m * 128 + ((c ^ (m & 15)) << 3)) = vv;
  }

  const int w = __builtin_amdgcn_readfirstlane(t >> 6);
  const int lane = t & 63, l = lane & 15, q = lane >> 4;
  const int j = w * 16 + l;

  bf16x8 Br[4], Bz[4], Bn[4];
#pragma unroll
  for (int ks = 0; ks < 4; ++ks) {
    const int ko = ks * 32 + q * 8;
    Br[ks] = *(const bf16x8*)(wih + (size_t)j * 128 + ko);
    Bz[ks] = *(const bf16x8*)(wih + (size_t)(128 + j) * 128 + ko);
    Bn[ks] = *(const bf16x8*)(wih + (size_t)(256 + j) * 128 + ko);
  }
  const float bR = b_ih[j] + b_hh[j];
  const float bZ = b_ih[128 + j] + b_hh[128 + j];
  const float bN = b_ih[256 + j];
  const float bH = b_hh[256 + j];

  f32x4 Cr[4] = {{0,0,0,0},{0,0,0,0},{0,0,0,0},{0,0,0,0}};
  f32x4 Cz[4] = {{0,0,0,0},{0,0,0,0},{0,0,0,0},{0,0,0,0}};
  f32x4 Cn[4] = {{0,0,0,0},{0,0,0,0},{0,0,0,0},{0,0,0,0}};
  __syncthreads();

#pragma unroll
  for (int ks = 0; ks < 4; ++ks) {
    bf16x8 A[4];
#pragma unroll
    for (int mt = 0; mt < 4; ++mt) {
      int m = mt * 16 + l, c = ks * 4 + q;
      A[mt] = *(const bf16x8*)(lds + m * 128 + (((c ^ l) & 15) << 3));
    }
#pragma unroll
    for (int mt = 0; mt < 4; ++mt) {
      Cr[mt] = mfma16(A[mt], Br[ks], Cr[mt]);
      Cz[mt] = mfma16(A[mt], Bz[ks], Cz[mt]);
      Cn[mt] = mfma16(A[mt], Bn[ks], Cn[mt]);
    }
  }

#pragma unroll
  for (int mt = 0; mt < 4; ++mt)
#pragma unroll
    for (int e = 0; e < 4; ++e) {
      int b = mt * 16 + q * 4 + e;              // C/D: col=lane&15, row=quad*4+reg
      float r  = sigm(Cr[mt][e] + bR);
      float z  = sigm(Cz[mt][e] + bZ);
      float nv = tanhf_(Cn[mt][e] + bN + r * bH);
      float hv = (1.0f - z) * nv;
      hvb[b * 128 + (j ^ (q << 4))] = f2b(hv);
    }
  __syncthreads();

#pragma unroll
  for (int i = 0; i < 2; ++i) {
    int g = t + 512 * i;
    int b = g >> 4, c8 = (g & 15) * 8;
    int qq = (b >> 2) & 3;
    if (base + b < 50000) {
      uint4 v = *(const uint4*)(hvb + b * 128 + (c8 ^ (qq << 4)));
      *(uint4*)(H + (size_t)(base + b) * 128 + c8) = v;
    }
  }
}

// ---------------------------------------------------------------------------
// FUSED attn+gru, half-node blocks: grid 2n, block 512 (8 waves).
// Block (p, half) handles batch rows half*32..+32 of parent p.
// Phase A: stage 4 children x 32 rows into chs[128][128]; u = ch·sent_w via
//   MFMA (wave: 64 rows x 32 cols); s/softmax (32-thread step); h0 -> regs.
//   LEAF: child max -> regs.
// Phase B: A-tile (x||h0) 32x256 in chs[0..16K); gru MFMA K=256 (B triple
//   loop-loaded, 1-deep prefetch); gates; hv -> chs[16K..24K) -> hout.
// Atomics once at true kernel end.
// ---------------------------------------------------------------------------
template <bool LEAF>
__global__ __launch_bounds__(512, 4) void attn_gru(
    const unsigned short* __restrict__ hch,   // child h (non-leaf), rows p*256..
    const int*            __restrict__ tokc,  // LEAF: children tokens
    const unsigned short* __restrict__ hleaf, // LEAF: per-vocab leaf h
    const unsigned short* __restrict__ swt,   // 128x128 bf16 [k_u][h]
    const float*          __restrict__ sb,
    const float*          __restrict__ ctx,
    const int*            __restrict__ tok,   // THIS level's tokens
    const unsigned short* __restrict__ embb,
    const unsigned short* __restrict__ wih,
    const unsigned short* __restrict__ whh,
    const float*          __restrict__ b_ih,
    const float*          __restrict__ b_hh,
    unsigned short*       __restrict__ hout,
    unsigned*             __restrict__ acc)
{
  __shared__ unsigned short chs[128 * 128];   // 32 KB, phase-aliased
  __shared__ float spart[4][128];
  __shared__ float alf[128];
  unsigned short* const atile = chs;          // phase B: 32x256 A tile (16 KB)
  unsigned short* const hvb   = chs + 8192;   // phase B: hv staging (8 KB)

  const int p2 = blockIdx.x;
  const int p = p2 >> 1, half = p2 & 1;
  const int t = threadIdx.x;

  // x gather for this half-node (1 chunk/thread) — issued at block start
  const int sm = t >> 4, sc = t & 15;
  const int* tp = tok + p * 64 + half * 32;
  uint4 px = *(const uint4*)(embb + (size_t)tp[sm] * 128 + sc * 8);

  // stage 128 child rows (4 children x 32 batch rows), XOR-swizzled
  if constexpr (LEAF) {
    const int* tokp = tokc + p * 256;
#pragma unroll
    for (int i = 0; i < 4; ++i) {
      int g = t + 512 * i, m = g >> 4, c = g & 15;
      int bg = (m >> 5) * 64 + half * 32 + (m & 31);
      uint4 v = *(const uint4*)(hleaf + (size_t)tokp[bg] * 128 + c * 8);
      *(uint4*)(chs + m * 128 + ((c ^ (m & 15)) << 3)) = v;
    }
  } else {
#pragma unroll
    for (int i = 0; i < 4; ++i) {
      int g = t + 512 * i, m = g >> 4, c = g & 15;
      int bg = (m >> 5) * 64 + half * 32 + (m & 31);
      uint4 v = *(const uint4*)(hch + ((size_t)p * 256 + bg) * 128 + c * 8);
      *(uint4*)(chs + m * 128 + ((c ^ (m & 15)) << 3)) = v;
    }
  }

  const int w = __builtin_amdgcn_readfirstlane(t >> 6);
  const int wm = w >> 2, wn = w & 3;          // wm: row-half (64), wn: col-32
  const int lane = t & 63, l = lane & 15, q = lane >> 4;
  const int j = w * 16 + l;

  bf16x8 Bs[2][4];
#pragma unroll
  for (int nt = 0; nt < 2; ++nt)
#pragma unroll
    for (int ks = 0; ks < 4; ++ks)
      Bs[nt][ks] = *(const bf16x8*)(swt + (size_t)(wn * 32 + nt * 16 + l) * 128 + ks * 32 + q * 8);

  f32x4 Cu[4][2] = {};
  __syncthreads();                                          // (1) chs staged

#pragma unroll
  for (int ks = 0; ks < 4; ++ks) {
#pragma unroll
    for (int mt = 0; mt < 4; ++mt) {
      int m = wm * 64 + mt * 16 + l;
      int c = ks * 4 + q;
      bf16x8 A = *(const bf16x8*)(chs + m * 128 + (((c ^ (m & 15)) & 15) << 3));
      Cu[mt][0] = mfma16(A, Bs[0][ks], Cu[mt][0]);
      Cu[mt][1] = mfma16(A, Bs[1][ks], Cu[mt][1]);
    }
  }

  const float sb0 = sb[wn * 32 + l],  sb1 = sb[wn * 32 + 16 + l];
  const float cx0 = ctx[wn * 32 + l], cx1 = ctx[wn * 32 + 16 + l];
#pragma unroll
  for (int mt = 0; mt < 4; ++mt) {
    float pe[4];
#pragma unroll
    for (int e = 0; e < 4; ++e)
      pe[e] = tanhf_(Cu[mt][0][e] + sb0) * cx0 + tanhf_(Cu[mt][1][e] + sb1) * cx1;
#pragma unroll
    for (int mask = 1; mask < 16; mask <<= 1)
#pragma unroll
      for (int e = 0; e < 4; ++e)
        pe[e] += __shfl_xor(pe[e], mask, 16);
    if (l == 0) {
      int r = wm * 64 + mt * 16 + q * 4;
#pragma unroll
      for (int e = 0; e < 4; ++e) spart[wn][r + e] = pe[e];
    }
  }
  __syncthreads();                                          // (2)

  if (t < 32) {                 // combine + softmax over a, one thread per rb
    float sv[4];
#pragma unroll
    for (int a = 0; a < 4; ++a) {
      int r = a * 32 + t;
      sv[a] = tanhf_(spart[0][r] + spart[1][r] + spart[2][r] + spart[3][r]);
    }
    float m = fmaxf(fmaxf(sv[0], sv[1]), fmaxf(sv[2], sv[3]));
    float e0 = __expf(sv[0] - m), e1 = __expf(sv[1] - m);
    float e2 = __expf(sv[2] - m), e3 = __expf(sv[3] - m);
    float inv = 1.0f / (e0 + e1 + e2 + e3);
    alf[t] = e0 * inv; alf[32 + t] = e1 * inv; alf[64 + t] = e2 * inv; alf[96 + t] = e3 * inv;
  }
  __syncthreads();                                          // (3)

  // alpha-weighted sum -> registers (thread t: row rb=t>>4, chunk c=t&15)
  float o[8] = {0, 0, 0, 0, 0, 0, 0, 0};
  {
    int rb = t >> 4, c = t & 15;
#pragma unroll
    for (int a = 0; a < 4; ++a) {
      int m = a * 32 + rb;
      const unsigned short* rp = chs + m * 128 + ((c ^ (m & 15)) << 3);
      float al = alf[m];
#pragma unroll
      for (int k = 0; k < 8; ++k) o[k] += al * b2f(rp[k]);
    }
  }

  // LEAF: children max, lane-contiguous mapping (acc word = half*4096+t+512e)
  float mxv[8];
  if constexpr (LEAF) {
    const int jj = t & 127, cc = jj >> 3;
#pragma unroll
    for (int e = 0; e < 8; ++e) mxv[e] = -1e30f;
#pragma unroll
    for (int a = 0; a < 4; ++a)
#pragma unroll
      for (int e = 0; e < 8; ++e) {
        int rb = (t >> 7) + 4 * e, m = a * 32 + rb;
        float v = b2f(chs[m * 128 + (((cc ^ (m & 15)) & 15) << 3) + (jj & 7)]);
        mxv[e] = fmaxf(mxv[e], v);
      }
  }
  __syncthreads();                                          // (4) chs reads done

  // build gru A tile: x chunks 0..15, h0 chunks 16..31
  *(uint4*)(atile + sm * 256 + ((sc ^ (sm & 15)) << 3)) = px;
  {
    int rb = t >> 4, c = t & 15;
    ushort4 ha, hb;
    ha.x = f2b(o[0]); ha.y = f2b(o[1]); ha.z = f2b(o[2]); ha.w = f2b(o[3]);
    hb.x = f2b(o[4]); hb.y = f2b(o[5]); hb.z = f2b(o[6]); hb.w = f2b(o[7]);
    unsigned short* dst = atile + rb * 256 + ((16 | ((c ^ (rb & 15)) & 15)) << 3);
    *(ushort4*)dst = ha;
    *(ushort4*)(dst + 4) = hb;
  }

  const unsigned short* wI = wih + (size_t)j * 128 + q * 8;
  const unsigned short* wH = whh + (size_t)j * 128 + q * 8;
  const float bR = b_ih[j] + b_hh[j];
  const float bZ = b_ih[128 + j] + b_hh[128 + j];
  const float bN = b_ih[256 + j];
  const float bH = b_hh[256 + j];
  __syncthreads();                                          // (5) A tile ready

  f32x4 Cr[2] = {{0,0,0,0},{0,0,0,0}};
  f32x4 Cz[2] = {{0,0,0,0},{0,0,0,0}};
  f32x4 Cn[2] = {{0,0,0,0},{0,0,0,0}};
  f32x4 Ch[2] = {{0,0,0,0},{0,0,0,0}};

  bf16x8 b0 = *(const bf16x8*)(wI);
  bf16x8 b1 = *(const bf16x8*)(wI + 128 * 128);
  bf16x8 b2 = *(const bf16x8*)(wI + 256 * 128);

#pragma unroll
  for (int ks = 0; ks < 8; ++ks) {
    bf16x8 c0 = b0, c1 = b1, c2 = b2;
    if (ks + 1 < 8) {                         // prefetch next B triple
      const unsigned short* base = (ks + 1 >= 4) ? wH : wI;
      const int ko = ((ks + 1) & 3) * 32;
      b0 = *(const bf16x8*)(base + ko);
      b1 = *(const bf16x8*)(base + 128 * 128 + ko);
      b2 = *(const bf16x8*)(base + 256 * 128 + ko);
    }
#pragma unroll
    for (int mt = 0; mt < 2; ++mt) {
      int m = mt * 16 + l;
      int c = ks * 4 + q;
      bf16x8 Amt = *(const bf16x8*)(atile + m * 256 + (((c & 16) | ((c ^ l) & 15)) << 3));
      Cr[mt] = mfma16(Amt, c0, Cr[mt]);
      Cz[mt] = mfma16(Amt, c1, Cz[mt]);
      if (ks < 4) Cn[mt] = mfma16(Amt, c2, Cn[mt]);
      else        Ch[mt] = mfma16(Amt, c2, Ch[mt]);
    }
  }

  // gates; hv -> hvb (q-swizzled); per-thread max in regs
  float mx[2][4];
#pragma unroll
  for (int mt = 0; mt < 2; ++mt) {
#pragma unroll
    for (int e = 0; e < 4; ++e) {
      const int b = mt * 16 + q * 4 + e;        // C/D: col=lane&15, row=quad*4+reg
      float r  = sigm(Cr[mt][e] + bR);
      float z  = sigm(Cz[mt][e] + bZ);
      float nv = tanhf_(Cn[mt][e] + bN + r * (Ch[mt][e] + bH));
      int c16 = j >> 3;
      float hp = b2f(atile[b * 256 + ((16 | ((c16 ^ (b & 15)) & 15)) << 3) + (j & 7)]);
      float hv = (1.0f - z) * nv + z * hp;
      hvb[b * 128 + (j ^ (q << 4))] = f2b(hv);
      mx[mt][e] = hv;
    }
  }
  __syncthreads();                                          // (6) hvb ready

  // coalesced hout store (1 chunk/thread)
  {
    int qq = (sm >> 2) & 3;
    uint4 v = *(const uint4*)(hvb + sm * 128 + ((sc * 8) ^ (qq << 4)));
    *(uint4*)(hout + ((size_t)p * 64 + half * 32 + sm) * 128 + sc * 8) = v;
  }

  // atomics at TRUE kernel end (no barrier after)
  unsigned* accs = acc + (p2 & 31) * 8192;
#pragma unroll
  for (int mt = 0; mt < 2; ++mt)
#pragma unroll
    for (int e = 0; e < 4; ++e) {
      const int bg = half * 32 + mt * 16 + q * 4 + e;
      atomicMax(accs + bg * 128 + j, fenc(mx[mt][e]));
    }
  if constexpr (LEAF) {
#pragma unroll
    for (int e = 0; e < 8; ++e)
      atomicMax(accs + half * 4096 + t + 512 * e, fenc(mxv[e]));
  }
}

extern "C" void kernel_launch(void* const* d_in, const int* in_sizes, int n_in,
                              void* d_out, int out_size, void* d_ws, size_t ws_size,
                              hipStream_t stream) {
  const int*   tokens = (const int*)d_in[0];
  const float* emb    = (const float*)d_in[1];
  const float* sent_w = (const float*)d_in[2];
  const float* sent_b = (const float*)d_in[3];
  const float* ctx_w  = (const float*)d_in[4];
  const float* w_ih   = (const float*)d_in[5];
  const float* w_hh   = (const float*)d_in[6];
  const float* b_ih   = (const float*)d_in[7];
  const float* b_hh   = (const float*)d_in[8];

  char* ws = (char*)d_ws;
  unsigned*       acc  = (unsigned*)(ws + WS_ACC);
  unsigned short* wihb = (unsigned short*)(ws + WS_WIH);
  unsigned short* whhb = (unsigned short*)(ws + WS_WHH);
  unsigned short* swtb = (unsigned short*)(ws + WS_SWT);
  unsigned short* embb = (unsigned short*)(ws + WS_EMBB);
  unsigned short* hlf  = (unsigned short*)(ws + WS_HLEAF);
  unsigned short* hA   = (unsigned short*)(ws + WS_HA);
  unsigned short* hB   = (unsigned short*)(ws + WS_HB);

  hipLaunchKernelGGL(prep_all, dim3(7722), dim3(256), 0, stream,
                     emb, w_ih, w_hh, sent_w, embb, wihb, whhb, swtb, acc);
  hipLaunchKernelGGL(prep_hleaf, dim3(782), dim3(512), 0, stream,
                     embb, wihb, b_ih, b_hh, hlf);

  static const int offs[7] = {0, 1, 5, 21, 85, 341, 1365};
  const int* tok6 = tokens + (size_t)1365 * 64;

  for (int d = 5; d >= 0; --d) {
    int n = 1 << (2 * d);
    unsigned short* hout  = (d & 1) ? hB : hA;
    unsigned short* child = (d & 1) ? hA : hB;   // level d+1 output (non-leaf)
    if (d == 5) {
      hipLaunchKernelGGL((attn_gru<true>), dim3(2 * n), dim3(512), 0, stream,
                         (const unsigned short*)nullptr, tok6, hlf,
                         swtb, sent_b, ctx_w,
                         tokens + (size_t)offs[5] * 64, embb, wihb, whhb,
                         b_ih, b_hh, hout, acc);
    } else {
      hipLaunchKernelGGL((attn_gru<false>), dim3(2 * n), dim3(512), 0, stream,
                         child, (const int*)nullptr, (const unsigned short*)nullptr,
                         swtb, sent_b, ctx_w,
                         tokens + (size_t)offs[d] * 64, embb, wihb, whhb,
                         b_ih, b_hh, hout, acc);
    }
  }
  hipLaunchKernelGGL(decode_out, dim3(32), dim3(256), 0, stream, acc, (float*)d_out);
}